// Round 10
// baseline (447.293 us; speedup 1.0000x reference)
//
#include <hip/hip_runtime.h>
#include <hip/hip_bf16.h>

// DenseDSSnetwork: 4-layer DSS-GIN over 4096 node-deleted subgraphs + graph branch.
// Inputs fp32, OUTPUT fp32 [64,10]. bf16 MFMA (16x16x32), fp32 accumulate.
// Round 10: bnred fence-fusion reverted (split bnred/bnfin, no device fences);
// k_gin: direct global hT store from mm3 registers (4->3 barriers, no LDS bounce),
// load-first staging order.

typedef __bf16 bf16x8 __attribute__((ext_vector_type(8)));
typedef float f32x4 __attribute__((ext_vector_type(4)));
typedef unsigned short us8 __attribute__((ext_vector_type(8)));
typedef unsigned short us4 __attribute__((ext_vector_type(4)));
typedef unsigned u32x4 __attribute__((ext_vector_type(4)));
typedef unsigned u32x2 __attribute__((ext_vector_type(2)));

__device__ __forceinline__ unsigned short f2b(float f) {
  unsigned u = __builtin_bit_cast(unsigned, f);
  u += 0x7FFFu + ((u >> 16) & 1u);            // RNE (cold paths)
  return (unsigned short)(u >> 16);
}
// HW packed convert: lo -> bits[15:0], hi -> bits[31:16], RNE
__device__ __forceinline__ unsigned cvtpk(float lo, float hi) {
  unsigned r;
  asm("v_cvt_pk_bf16_f32 %0, %1, %2" : "=v"(r) : "v"(lo), "v"(hi));
  return r;
}
__device__ __forceinline__ float b2f(unsigned short h) {
  return __builtin_bit_cast(float, (unsigned)h << 16);
}
__device__ __forceinline__ f32x4 mm(bf16x8 a, bf16x8 b, f32x4 c) {
  return __builtin_amdgcn_mfma_f32_16x16x32_bf16(a, b, c, 0, 0, 0);
}
__device__ __forceinline__ bf16x8 frag(const char* base, int row, int Kelems, int k0) {
  int off = (row * Kelems + k0) * 2;
  off ^= (row & 7) << 4;
  return *(const bf16x8*)(base + off);
}
__device__ __forceinline__ float lk(float v) { return fmaxf(v, 0.01f * v); }

// Weight prep: W[k][n] fp32 -> Wt[n][k] bf16, 16 matrices
__global__ __launch_bounds__(256) void k_prep(const float* __restrict__ g1,
    const float* __restrict__ g2, const float* __restrict__ s1,
    const float* __restrict__ s2, unsigned short* __restrict__ wt) {
  int b = blockIdx.x;
  int l = b >> 2, j = b & 3;
  const float* src = (j == 0 ? g1 : j == 1 ? g2 : j == 2 ? s1 : s2) + l * 16384;
  unsigned short* dst = wt + b * 16384;
  for (int e = threadIdx.x; e < 16384; e += 256) {
    int n = e >> 7, k = e & 127;
    dst[e] = f2b(src[k * 128 + n]);
  }
}

// adj fp32 (0/1) -> 1 bit. blocks 0..4095: adj->badj; 4096..4159: oadj->boadj.
__global__ __launch_bounds__(256) void k_pack(const float* __restrict__ adj,
    const float* __restrict__ oadj, unsigned short* __restrict__ badj,
    unsigned short* __restrict__ boadj) {
  int bid = blockIdx.x, t = threadIdx.x;
  bool SUB = bid < 4096;
  int sub = SUB ? bid : bid - 4096;
  const float* src = SUB ? adj : oadj;
  unsigned short* dst = SUB ? badj : boadj;
  const float* p = src + (size_t)sub * 4096 + (t >> 2) * 64 + (t & 3) * 16;
  unsigned bits = 0;
  #pragma unroll
  for (int j4 = 0; j4 < 4; ++j4) {
    float4 v = *(const float4*)(p + j4 * 4);
    bits |= (unsigned)(v.x != 0.f) << (j4 * 4);
    bits |= (unsigned)(v.y != 0.f) << (j4 * 4 + 1);
    bits |= (unsigned)(v.z != 0.f) << (j4 * 4 + 2);
    bits |= (unsigned)(v.w != 0.f) << (j4 * 4 + 3);
  }
  dst[(size_t)sub * 256 + t] = (unsigned short)bits;
}

// layer-0: cast x fp32->bf16 AND produce xsum partials (row-major).
__global__ __launch_bounds__(256) void k_castseg(const float* __restrict__ x,
    unsigned short* __restrict__ xw, float* __restrict__ pxs) {
  int b2 = blockIdx.x, bb = b2 >> 2, c = b2 & 3, t = threadIdx.x;
  int e0 = c * 2048 + t * 8;
  float acc[8];
  #pragma unroll
  for (int j = 0; j < 8; ++j) acc[j] = 0.f;
  for (int ss = 0; ss < 16; ++ss) {
    size_t sb = ((size_t)bb * 16 + ss) * 8192 + e0;
    float4 v0 = *(const float4*)(x + sb);
    float4 v1 = *(const float4*)(x + sb + 4);
    acc[0] += v0.x; acc[1] += v0.y; acc[2] += v0.z; acc[3] += v0.w;
    acc[4] += v1.x; acc[5] += v1.y; acc[6] += v1.z; acc[7] += v1.w;
    u32x4 pk;
    pk.x = cvtpk(v0.x, v0.y); pk.y = cvtpk(v0.z, v0.w);
    pk.z = cvtpk(v1.x, v1.y); pk.w = cvtpk(v1.z, v1.w);
    *(us8*)(xw + sb) = __builtin_bit_cast(us8, pk);
  }
  float* o = pxs + (size_t)bb * 8192 + e0;
  *(float4*)o = make_float4(acc[0], acc[1], acc[2], acc[3]);
  *(float4*)(o + 4) = make_float4(acc[4], acc[5], acc[6], acc[7]);
}

// x recompute (feature-major) + segmean partials, or pool partials at LAST.
template<int LAST>
__global__ __launch_bounds__(256) void k_xpart(const unsigned short* __restrict__ h1T,
    const unsigned short* __restrict__ h2T, const float* __restrict__ bnA,
    const float* __restrict__ bnB, const float* __restrict__ bnsA,
    const float* __restrict__ bnsB, float* __restrict__ pxsT,
    float* __restrict__ ppool) {
  int b2 = blockIdx.x, bb = b2 >> 2, c = b2 & 3, g = bb >> 2;
  int t = threadIdx.x;
  int d = c * 32 + (t >> 3), n0 = (t & 7) * 8;
  size_t off = (size_t)d * 64 + n0;
  float A1 = bnA[d], B1 = bnB[d];
  float A2 = bnsA[d], B2 = bnsB[d];
  float hb[8];
  {
    us8 v = *(const us8*)(h2T + (size_t)g * 8192 + off);
    #pragma unroll
    for (int j = 0; j < 8; ++j) hb[j] = fmaf(b2f(v[j]), A2, B2);
  }
  float acc[8];
  #pragma unroll
  for (int j = 0; j < 8; ++j) acc[j] = 0.f;
  for (int ss = 0; ss < 16; ++ss) {
    int s = bb * 16 + ss;
    int del = s & 63;
    us8 a = *(const us8*)(h1T + (size_t)s * 8192 + off);
    #pragma unroll
    for (int j = 0; j < 8; ++j) {
      float hv = ((n0 + j) != del) ? fmaf(b2f(a[j]), A1, B1) : 0.f;
      acc[j] += lk(hv + hb[j]);
    }
  }
  if (!LAST) {
    float* o = pxsT + (size_t)bb * 8192 + off;
    *(float4*)o       = make_float4(acc[0], acc[1], acc[2], acc[3]);
    *(float4*)(o + 4) = make_float4(acc[4], acc[5], acc[6], acc[7]);
  } else {
    float s8 = ((acc[0] + acc[1]) + (acc[2] + acc[3])) + ((acc[4] + acc[5]) + (acc[6] + acc[7]));
    s8 += __shfl_xor(s8, 1, 64);
    s8 += __shfl_xor(s8, 2, 64);
    s8 += __shfl_xor(s8, 4, 64);
    if ((t & 7) == 0) ppool[(size_t)bb * 128 + d] = s8;
  }
}

// Fused GIN, merged grid: blocks 0..4095 subgraph branch, 4096..4159 graph branch.
// 3 barriers; mm3 writes hT straight to global from registers.
template<int FIRST>
__global__ __launch_bounds__(512, 4) void k_gin(
    const unsigned short* __restrict__ xw, unsigned short* __restrict__ h1T,
    const unsigned short* __restrict__ h2prev, unsigned short* __restrict__ h2out,
    const float* __restrict__ pxs,
    const unsigned short* __restrict__ badj, const unsigned short* __restrict__ boadj,
    const unsigned short* __restrict__ W1g, const unsigned short* __restrict__ W2g,
    const unsigned short* __restrict__ W1s, const unsigned short* __restrict__ W2s,
    const float* __restrict__ b1g, const float* __restrict__ b2g,
    const float* __restrict__ b1s, const float* __restrict__ b2s,
    const float* __restrict__ epg, const float* __restrict__ epss,
    const float* __restrict__ bnA, const float* __restrict__ bnB,
    const float* __restrict__ bnsA, const float* __restrict__ bnsB,
    float* __restrict__ p1s, float* __restrict__ p1q,
    float* __restrict__ p2s, float* __restrict__ p2q) {
  __shared__ __align__(16) char lds[40960];
  char* ldsAdj = lds;              // 8KB : bf16 [64][64] swz (adj + ep1*I)
  char* ldsB   = lds + 8192;       // 16KB: x^T [128][64] swz, then u [64][128] swz
  char* ldsC   = lds + 24576;      // 16KB: FIRST x_rm linear; t [64][128] swz

  const int tid = threadIdx.x;
  const int bid = blockIdx.x;
  const bool SUB = bid < 4096;
  const int lb = SUB ? bid : bid - 4096;
  const int wv = tid >> 6, ln = tid & 63;
  const int lr = ln & 15, lkh = ln >> 4;
  const int wrow = wv * 16 + lr;
  const float ep1 = 1.0f + (SUB ? epg[0] : epss[0]);
  const int del = SUB ? (bid & 63) : -1;
  const unsigned short* W1t = SUB ? W1g : W1s;
  const unsigned short* W2t = SUB ? W2g : W2s;

  // ---- W fragments into registers ----
  bf16x8 w1f[4], w2f[4];
  #pragma unroll
  for (int kk = 0; kk < 4; ++kk) {
    w1f[kk] = *(const bf16x8*)(W1t + (size_t)wrow * 128 + kk * 32 + lkh * 8);
    w2f[kk] = *(const bf16x8*)(W2t + (size_t)wrow * 128 + kk * 32 + lkh * 8);
  }
  const float bb1 = (SUB ? b1g : b1s)[wrow];
  const float bb2 = (SUB ? b2g : b2s)[wrow];

  // ---- load-first: adj bits byte ----
  const unsigned char* bits =
      (const unsigned char*)(SUB ? badj + (size_t)lb * 256 : boadj + (size_t)lb * 256);
  unsigned char bbt = bits[tid];

  // ---- stage x (loads issued before adj LDS writes) ----
  if (FIRST) {
    if (SUB) {
      const unsigned short* xg = xw + (size_t)bid * 8192;
      us8 x0 = *(const us8*)(xg + tid * 8);
      us8 x1 = *(const us8*)(xg + tid * 8 + 4096);
      // adj expand + LDS write (overlaps x loads)
      {
        int row = tid >> 3, o = tid & 7;
        unsigned short ep1b = f2b(ep1);
        us8 v;
        #pragma unroll
        for (int j = 0; j < 8; ++j) v[j] = ((bbt >> j) & 1) ? (unsigned short)0x3F80 : (unsigned short)0;
        int j0 = row - o * 8;
        if (j0 >= 0 && j0 < 8) v[j0] = ep1b;
        *(us8*)(ldsAdj + ((tid * 16) ^ ((row & 7) << 4))) = v;
      }
      *(us8*)(ldsC + tid * 16) = x0;
      *(us8*)(ldsC + tid * 16 + 8192) = x1;
    } else {
      // adj expand first (graph branch)
      {
        int row = tid >> 3, o = tid & 7;
        unsigned short ep1b = f2b(ep1);
        us8 v;
        #pragma unroll
        for (int j = 0; j < 8; ++j) v[j] = ((bbt >> j) & 1) ? (unsigned short)0x3F80 : (unsigned short)0;
        int j0 = row - o * 8;
        if (j0 >= 0 && j0 < 8) v[j0] = ep1b;
        *(us8*)(ldsAdj + ((tid * 16) ^ ((row & 7) << 4))) = v;
      }
      const float* p = pxs + (size_t)lb * 4 * 8192;
      int e0 = tid * 16;
      #pragma unroll
      for (int cc = 0; cc < 4; ++cc) {
        float4 s = {0.f, 0.f, 0.f, 0.f};
        #pragma unroll
        for (int qt = 0; qt < 4; ++qt) {
          float4 v = *(const float4*)(p + qt * 8192 + e0 + cc * 4);
          s.x += v.x; s.y += v.y; s.z += v.z; s.w += v.w;
        }
        u32x2 pk;
        pk.x = cvtpk(s.x * 0.015625f, s.y * 0.015625f);
        pk.y = cvtpk(s.z * 0.015625f, s.w * 0.015625f);
        *(us4*)(ldsC + (e0 + cc * 4) * 2) = __builtin_bit_cast(us4, pk);
      }
    }
    __syncthreads();
    // transpose x_rm -> ldsB = x^T [128][64] swz
    int d = tid & 127, mg = (tid >> 7) * 16;
    #pragma unroll
    for (int mb = 0; mb < 16; mb += 8) {
      us8 v;
      #pragma unroll
      for (int j = 0; j < 8; ++j)
        v[j] = *(const unsigned short*)(ldsC + ((mg + mb + j) << 8) + (d << 1));
      *(us8*)(ldsB + (((d << 7) + ((mg + mb) << 1)) ^ ((d & 7) << 4))) = v;
    }
  } else {
    int d = tid >> 2, n0 = (tid & 3) * 16;    // feature row, 16 nodes
    if (SUB) {
      const unsigned short* h1g = h1T + (size_t)bid * 8192 + d * 64 + n0;
      const unsigned short* h2g = h2prev + (size_t)(bid >> 6) * 8192 + d * 64 + n0;
      us8 a0 = *(const us8*)(h1g);
      us8 a1 = *(const us8*)(h1g + 8);
      us8 b0 = *(const us8*)(h2g);
      us8 b1 = *(const us8*)(h2g + 8);
      // adj expand + LDS write while h1/h2 loads are in flight
      {
        int row = tid >> 3, o = tid & 7;
        unsigned short ep1b = f2b(ep1);
        us8 v;
        #pragma unroll
        for (int j = 0; j < 8; ++j) v[j] = ((bbt >> j) & 1) ? (unsigned short)0x3F80 : (unsigned short)0;
        int j0 = row - o * 8;
        if (j0 >= 0 && j0 < 8) v[j0] = ep1b;
        *(us8*)(ldsAdj + ((tid * 16) ^ ((row & 7) << 4))) = v;
      }
      float A1 = bnA[d], B1 = bnB[d];
      float A2 = bnsA[d], B2 = bnsB[d];
      us8 av[2] = {a0, a1}, bv[2] = {b0, b1};
      #pragma unroll
      for (int cc = 0; cc < 2; ++cc) {
        float xv[8];
        #pragma unroll
        for (int j = 0; j < 8; ++j) {
          int m = n0 + cc * 8 + j;
          float hv = (m != del) ? fmaf(b2f(av[cc][j]), A1, B1) : 0.f;
          xv[j] = lk(hv + fmaf(b2f(bv[cc][j]), A2, B2));
        }
        u32x4 pk;
        pk.x = cvtpk(xv[0], xv[1]); pk.y = cvtpk(xv[2], xv[3]);
        pk.z = cvtpk(xv[4], xv[5]); pk.w = cvtpk(xv[6], xv[7]);
        *(us8*)(ldsB + (((d * 64 + n0 + cc * 8) * 2) ^ ((d & 7) << 4))) = __builtin_bit_cast(us8, pk);
      }
    } else {
      {
        int row = tid >> 3, o = tid & 7;
        unsigned short ep1b = f2b(ep1);
        us8 v;
        #pragma unroll
        for (int j = 0; j < 8; ++j) v[j] = ((bbt >> j) & 1) ? (unsigned short)0x3F80 : (unsigned short)0;
        int j0 = row - o * 8;
        if (j0 >= 0 && j0 < 8) v[j0] = ep1b;
        *(us8*)(ldsAdj + ((tid * 16) ^ ((row & 7) << 4))) = v;
      }
      const float* p = pxs + (size_t)lb * 4 * 8192 + d * 64 + n0;  // pxsT
      #pragma unroll
      for (int cc = 0; cc < 4; ++cc) {
        float4 s = {0.f, 0.f, 0.f, 0.f};
        #pragma unroll
        for (int qt = 0; qt < 4; ++qt) {
          float4 v = *(const float4*)(p + qt * 8192 + cc * 4);
          s.x += v.x; s.y += v.y; s.z += v.z; s.w += v.w;
        }
        u32x2 pk;
        pk.x = cvtpk(s.x * 0.015625f, s.y * 0.015625f);
        pk.y = cvtpk(s.z * 0.015625f, s.w * 0.015625f);
        *(us4*)(ldsB + (((d * 64 + n0 + cc * 4) * 2) ^ ((d & 7) << 4))) = __builtin_bit_cast(us4, pk);
      }
    }
  }
  __syncthreads();

  // ---- mm1: t = (adj+ep1*I) @ x -> ldsC [64][128] swz ----
  {
    f32x4 acc[4] = {};
    #pragma unroll
    for (int rt = 0; rt < 4; ++rt) {
      #pragma unroll
      for (int k0 = 0; k0 < 64; k0 += 32) {
        bf16x8 a = frag(ldsAdj, rt * 16 + lr, 64, k0 + lkh * 8);
        bf16x8 b = frag(ldsB, wrow, 64, k0 + lkh * 8);
        acc[rt] = mm(a, b, acc[rt]);
      }
    }
    #pragma unroll
    for (int rt = 0; rt < 4; ++rt) {
      unsigned p01 = cvtpk(acc[rt][0], acc[rt][1]);
      unsigned p23 = cvtpk(acc[rt][2], acc[rt][3]);
      int r0 = rt * 16 + lkh * 4;
      *(unsigned short*)(ldsC + ((((r0 + 0) << 8) + (wrow << 1)) ^ (((r0 + 0) & 7) << 4))) = (unsigned short)p01;
      *(unsigned short*)(ldsC + ((((r0 + 1) << 8) + (wrow << 1)) ^ (((r0 + 1) & 7) << 4))) = (unsigned short)(p01 >> 16);
      *(unsigned short*)(ldsC + ((((r0 + 2) << 8) + (wrow << 1)) ^ (((r0 + 2) & 7) << 4))) = (unsigned short)p23;
      *(unsigned short*)(ldsC + ((((r0 + 3) << 8) + (wrow << 1)) ^ (((r0 + 3) & 7) << 4))) = (unsigned short)(p23 >> 16);
    }
  }
  __syncthreads();

  // ---- mm2: u = leaky(t @ W1 + b1) -> ldsB [64][128] swz ----
  #pragma unroll
  for (int rt = 0; rt < 4; ++rt) {
    f32x4 acc = {};
    #pragma unroll
    for (int kk = 0; kk < 4; ++kk) {
      bf16x8 a = frag(ldsC, rt * 16 + lr, 128, kk * 32 + lkh * 8);
      acc = mm(a, w1f[kk], acc);
    }
    float u0 = lk(acc[0] + bb1), u1 = lk(acc[1] + bb1);
    float u2 = lk(acc[2] + bb1), u3 = lk(acc[3] + bb1);
    unsigned p01 = cvtpk(u0, u1);
    unsigned p23 = cvtpk(u2, u3);
    int r0 = rt * 16 + lkh * 4;
    *(unsigned short*)(ldsB + ((((r0 + 0) << 8) + (wrow << 1)) ^ (((r0 + 0) & 7) << 4))) = (unsigned short)p01;
    *(unsigned short*)(ldsB + ((((r0 + 1) << 8) + (wrow << 1)) ^ (((r0 + 1) & 7) << 4))) = (unsigned short)(p01 >> 16);
    *(unsigned short*)(ldsB + ((((r0 + 2) << 8) + (wrow << 1)) ^ (((r0 + 2) & 7) << 4))) = (unsigned short)p23;
    *(unsigned short*)(ldsB + ((((r0 + 3) << 8) + (wrow << 1)) ^ (((r0 + 3) & 7) << 4))) = (unsigned short)(p23 >> 16);
  }
  __syncthreads();

  // ---- mm3: h = u @ W2 + b2, mask; DIRECT global hT store + reg BN partials ----
  {
    unsigned short* hout = SUB ? h1T + (size_t)bid * 8192 : h2out + (size_t)lb * 8192;
    float sm = 0.f, sq = 0.f;
    #pragma unroll
    for (int rt = 0; rt < 4; ++rt) {
      f32x4 acc = {};
      #pragma unroll
      for (int kk = 0; kk < 4; ++kk) {
        bf16x8 a = frag(ldsB, rt * 16 + lr, 128, kk * 32 + lkh * 8);
        acc = mm(a, w2f[kk], acc);
      }
      float v0 = acc[0] + bb2, v1 = acc[1] + bb2, v2 = acc[2] + bb2, v3 = acc[3] + bb2;
      int m0 = rt * 16 + lkh * 4;
      if (m0 + 0 == del) v0 = 0.f;
      if (m0 + 1 == del) v1 = 0.f;
      if (m0 + 2 == del) v2 = 0.f;
      if (m0 + 3 == del) v3 = 0.f;
      sm += v0 + v1 + v2 + v3;
      sq += v0 * v0 + v1 * v1 + v2 * v2 + v3 * v3;
      u32x2 pk;
      pk.x = cvtpk(v0, v1);
      pk.y = cvtpk(v2, v3);
      *(us4*)(hout + wrow * 64 + m0) = __builtin_bit_cast(us4, pk);
    }
    sm += __shfl_xor(sm, 16, 64); sm += __shfl_xor(sm, 32, 64);
    sq += __shfl_xor(sq, 16, 64); sq += __shfl_xor(sq, 32, 64);
    if (ln < 16) {
      float* ps = SUB ? p1s + (size_t)bid * 128 : p2s + (size_t)lb * 128;
      float* pq = SUB ? p1q + (size_t)bid * 128 : p2q + (size_t)lb * 128;
      ps[wrow] = sm;
      pq[wrow] = sq;
    }
  }
}

// BN stage-1 reduce, coalesced
__global__ __launch_bounds__(256) void k_bnred(const float* __restrict__ p1s,
    const float* __restrict__ p1q, float* __restrict__ q1s, float* __restrict__ q1q) {
  __shared__ float red[512];
  int b = blockIdx.x, tid = threadIdx.x;
  int d = tid & 127, jh = tid >> 7;
  float s = 0.f, q = 0.f;
  for (int j = b * 64 + jh; j < b * 64 + 64; j += 2) {
    s += p1s[(size_t)j * 128 + d];
    q += p1q[(size_t)j * 128 + d];
  }
  red[tid] = s; red[256 + tid] = q;
  __syncthreads();
  if (tid < 128) {
    q1s[(size_t)b * 128 + d] = red[d] + red[d + 128];
    q1q[(size_t)b * 128 + d] = red[256 + d] + red[384 + d];
  }
}

// Finalize BN into fused scale/shift
__global__ __launch_bounds__(128) void k_bnfin(const float* __restrict__ q1s,
    const float* __restrict__ q1q, const float* __restrict__ p2s,
    const float* __restrict__ p2q, const float* __restrict__ gam1,
    const float* __restrict__ bet1, const float* __restrict__ gam2,
    const float* __restrict__ bet2, float* __restrict__ bnA, float* __restrict__ bnB,
    float* __restrict__ bnsA, float* __restrict__ bnsB) {
  int d = threadIdx.x;
  float s = 0.f, q = 0.f, s2 = 0.f, q2 = 0.f;
  for (int j = 0; j < 64; ++j) {
    s  += q1s[j * 128 + d];  q  += q1q[j * 128 + d];
    s2 += p2s[j * 128 + d];  q2 += p2q[j * 128 + d];
  }
  const float cnt1 = 4096.0f * 63.0f;
  float mean = s / cnt1;
  float var = q / cnt1 - mean * mean;
  float A = gam1[d] * rsqrtf(var + 1e-5f);
  bnA[d] = A; bnB[d] = bet1[d] - mean * A;
  float mean2 = s2 / 4096.0f;
  float var2 = q2 / 4096.0f - mean2 * mean2;
  float A2 = gam2[d] * rsqrtf(var2 + 1e-5f);
  bnsA[d] = A2; bnsB[d] = bet2[d] - mean2 * A2;
}

// final readout MLP per graph, fp32 out
__global__ __launch_bounds__(256) void k_final(const float* __restrict__ ppool,
    const float* __restrict__ W1, const float* __restrict__ b1,
    const float* __restrict__ W2, const float* __restrict__ b2,
    float* __restrict__ out) {
  __shared__ float hg[128];
  __shared__ float z[256];
  int g = blockIdx.x, t = threadIdx.x;
  if (t < 128) {
    float s = ppool[(size_t)(g * 4 + 0) * 128 + t] + ppool[(size_t)(g * 4 + 1) * 128 + t]
            + ppool[(size_t)(g * 4 + 2) * 128 + t] + ppool[(size_t)(g * 4 + 3) * 128 + t];
    hg[t] = s * (1.0f / (63.0f * 64.0f));
  }
  __syncthreads();
  float a = b1[t];
  for (int d = 0; d < 128; ++d) a = fmaf(hg[d], W1[d * 256 + t], a);
  z[t] = lk(a);
  __syncthreads();
  if (t < 10) {
    float o = b2[t];
    for (int j = 0; j < 256; ++j) o = fmaf(z[j], W2[j * 10 + t], o);
    out[g * 10 + t] = o;
  }
}

extern "C" void kernel_launch(void* const* d_in, const int* in_sizes, int n_in,
                              void* d_out, int out_size, void* d_ws, size_t ws_size,
                              hipStream_t stream) {
  (void)in_sizes; (void)n_in; (void)out_size; (void)ws_size;
  const float* x    = (const float*)d_in[0];
  const float* adj  = (const float*)d_in[1];
  const float* oadj = (const float*)d_in[2];
  const float* gW1  = (const float*)d_in[3];
  const float* gb1  = (const float*)d_in[4];
  const float* gW2  = (const float*)d_in[5];
  const float* gb2  = (const float*)d_in[6];
  const float* geps = (const float*)d_in[7];
  const float* sW1  = (const float*)d_in[8];
  const float* sb1  = (const float*)d_in[9];
  const float* sW2  = (const float*)d_in[10];
  const float* sb2  = (const float*)d_in[11];
  const float* seps = (const float*)d_in[12];
  const float* bng  = (const float*)d_in[13];
  const float* bnb  = (const float*)d_in[14];
  const float* bnsg = (const float*)d_in[15];
  const float* bnsb = (const float*)d_in[16];
  const float* fW1  = (const float*)d_in[17];
  const float* fb1  = (const float*)d_in[18];
  const float* fW2  = (const float*)d_in[19];
  const float* fb2  = (const float*)d_in[20];
  float* out = (float*)d_out;

  char* w = (char*)d_ws;
  unsigned short* xw   = (unsigned short*)w; w += 67108864;   // x0 bf16 row-major
  unsigned short* h1T  = (unsigned short*)w; w += 67108864;   // h1 bf16 feature-major
  unsigned short* h2a  = (unsigned short*)w; w += 1048576;    // h2 ping (feature-major)
  unsigned short* h2b  = (unsigned short*)w; w += 1048576;    // h2 pong
  unsigned short* badj = (unsigned short*)w; w += 2097152;    // adj bits
  unsigned short* boadj= (unsigned short*)w; w += 32768;      // oadj bits
  unsigned short* wt   = (unsigned short*)w; w += 524288;     // 16x W^T bf16
  float* pxs  = (float*)w;          w += 8388608;             // xsum partials [256][8192]
  float* p1s  = (float*)w;          w += 2097152;
  float* p1q  = (float*)w;          w += 2097152;
  float* p2s  = (float*)w;          w += 32768;
  float* p2q  = (float*)w;          w += 32768;
  float* q1s  = (float*)w;          w += 32768;
  float* q1q  = (float*)w;          w += 32768;
  float* bnA  = (float*)w;          w += 512;
  float* bnB  = (float*)w;          w += 512;
  float* bnsA = (float*)w;          w += 512;
  float* bnsB = (float*)w;          w += 512;
  float* ppool= (float*)w;          w += 131072;              // [256][128]

  unsigned short* h2buf[2] = {h2a, h2b};

  k_prep<<<16, 256, 0, stream>>>(gW1, gW2, sW1, sW2, wt);
  k_pack<<<4160, 256, 0, stream>>>(adj, oadj, badj, boadj);
  k_castseg<<<1024, 256, 0, stream>>>(x, xw, pxs);

  for (int i = 0; i < 4; ++i) {
    unsigned short* h2prev = h2buf[(i + 1) & 1];   // layer i-1 output (i>=1)
    unsigned short* h2cur  = h2buf[i & 1];
    if (i > 0)
      k_xpart<0><<<1024, 256, 0, stream>>>(h1T, h2prev, bnA, bnB, bnsA, bnsB, pxs, ppool);
    if (i == 0)
      k_gin<1><<<4160, 512, 0, stream>>>(xw, h1T, h2prev, h2cur, pxs, badj, boadj,
          wt + 0 * 16384, wt + 1 * 16384, wt + 2 * 16384, wt + 3 * 16384,
          gb1, gb2, sb1, sb2, geps, seps, bnA, bnB, bnsA, bnsB, p1s, p1q, p2s, p2q);
    else
      k_gin<0><<<4160, 512, 0, stream>>>(xw, h1T, h2prev, h2cur, pxs, badj, boadj,
          wt + (i * 4 + 0) * 16384, wt + (i * 4 + 1) * 16384,
          wt + (i * 4 + 2) * 16384, wt + (i * 4 + 3) * 16384,
          gb1 + i * 128, gb2 + i * 128, sb1 + i * 128, sb2 + i * 128,
          geps + i, seps + i, bnA, bnB, bnsA, bnsB, p1s, p1q, p2s, p2q);
    k_bnred<<<64, 256, 0, stream>>>(p1s, p1q, q1s, q1q);
    k_bnfin<<<1, 128, 0, stream>>>(q1s, q1q, p2s, p2q, bng + i * 128,
        bnb + i * 128, bnsg + i * 128, bnsb + i * 128, bnA, bnB, bnsA, bnsB);
  }
  k_xpart<1><<<1024, 256, 0, stream>>>(h1T, h2buf[1], bnA, bnB, bnsA, bnsB, pxs, ppool);
  k_final<<<64, 256, 0, stream>>>(ppool, fW1, fb1, fW2, fb2, out);
}

// Round 11
// 420.832 us; speedup vs baseline: 1.0629x; 1.0629x over previous
//
#include <hip/hip_runtime.h>
#include <hip/hip_bf16.h>

// DenseDSSnetwork: 4-layer DSS-GIN over 4096 node-deleted subgraphs + graph branch.
// Inputs fp32, OUTPUT fp32 [64,10]. bf16 MFMA (16x16x32), fp32 accumulate.
// Round 11: re-anchor at round-8 best (422us): LDS-bounced coalesced hT write,
// split bnred/bnfin (no fences). Keeps merged k_pack from round 9.

typedef __bf16 bf16x8 __attribute__((ext_vector_type(8)));
typedef float f32x4 __attribute__((ext_vector_type(4)));
typedef unsigned short us8 __attribute__((ext_vector_type(8)));
typedef unsigned short us4 __attribute__((ext_vector_type(4)));
typedef unsigned u32x4 __attribute__((ext_vector_type(4)));
typedef unsigned u32x2 __attribute__((ext_vector_type(2)));

__device__ __forceinline__ unsigned short f2b(float f) {
  unsigned u = __builtin_bit_cast(unsigned, f);
  u += 0x7FFFu + ((u >> 16) & 1u);            // RNE (cold paths)
  return (unsigned short)(u >> 16);
}
// HW packed convert: lo -> bits[15:0], hi -> bits[31:16], RNE
__device__ __forceinline__ unsigned cvtpk(float lo, float hi) {
  unsigned r;
  asm("v_cvt_pk_bf16_f32 %0, %1, %2" : "=v"(r) : "v"(lo), "v"(hi));
  return r;
}
__device__ __forceinline__ float b2f(unsigned short h) {
  return __builtin_bit_cast(float, (unsigned)h << 16);
}
__device__ __forceinline__ f32x4 mm(bf16x8 a, bf16x8 b, f32x4 c) {
  return __builtin_amdgcn_mfma_f32_16x16x32_bf16(a, b, c, 0, 0, 0);
}
__device__ __forceinline__ bf16x8 frag(const char* base, int row, int Kelems, int k0) {
  int off = (row * Kelems + k0) * 2;
  off ^= (row & 7) << 4;
  return *(const bf16x8*)(base + off);
}
__device__ __forceinline__ float lk(float v) { return fmaxf(v, 0.01f * v); }

// Weight prep: W[k][n] fp32 -> Wt[n][k] bf16, 16 matrices
__global__ __launch_bounds__(256) void k_prep(const float* __restrict__ g1,
    const float* __restrict__ g2, const float* __restrict__ s1,
    const float* __restrict__ s2, unsigned short* __restrict__ wt) {
  int b = blockIdx.x;
  int l = b >> 2, j = b & 3;
  const float* src = (j == 0 ? g1 : j == 1 ? g2 : j == 2 ? s1 : s2) + l * 16384;
  unsigned short* dst = wt + b * 16384;
  for (int e = threadIdx.x; e < 16384; e += 256) {
    int n = e >> 7, k = e & 127;
    dst[e] = f2b(src[k * 128 + n]);
  }
}

// adj fp32 (0/1) -> 1 bit. blocks 0..4095: adj->badj; 4096..4159: oadj->boadj.
__global__ __launch_bounds__(256) void k_pack(const float* __restrict__ adj,
    const float* __restrict__ oadj, unsigned short* __restrict__ badj,
    unsigned short* __restrict__ boadj) {
  int bid = blockIdx.x, t = threadIdx.x;
  bool SUB = bid < 4096;
  int sub = SUB ? bid : bid - 4096;
  const float* src = SUB ? adj : oadj;
  unsigned short* dst = SUB ? badj : boadj;
  const float* p = src + (size_t)sub * 4096 + (t >> 2) * 64 + (t & 3) * 16;
  unsigned bits = 0;
  #pragma unroll
  for (int j4 = 0; j4 < 4; ++j4) {
    float4 v = *(const float4*)(p + j4 * 4);
    bits |= (unsigned)(v.x != 0.f) << (j4 * 4);
    bits |= (unsigned)(v.y != 0.f) << (j4 * 4 + 1);
    bits |= (unsigned)(v.z != 0.f) << (j4 * 4 + 2);
    bits |= (unsigned)(v.w != 0.f) << (j4 * 4 + 3);
  }
  dst[(size_t)sub * 256 + t] = (unsigned short)bits;
}

// layer-0: cast x fp32->bf16 AND produce xsum partials (row-major).
__global__ __launch_bounds__(256) void k_castseg(const float* __restrict__ x,
    unsigned short* __restrict__ xw, float* __restrict__ pxs) {
  int b2 = blockIdx.x, bb = b2 >> 2, c = b2 & 3, t = threadIdx.x;
  int e0 = c * 2048 + t * 8;
  float acc[8];
  #pragma unroll
  for (int j = 0; j < 8; ++j) acc[j] = 0.f;
  for (int ss = 0; ss < 16; ++ss) {
    size_t sb = ((size_t)bb * 16 + ss) * 8192 + e0;
    float4 v0 = *(const float4*)(x + sb);
    float4 v1 = *(const float4*)(x + sb + 4);
    acc[0] += v0.x; acc[1] += v0.y; acc[2] += v0.z; acc[3] += v0.w;
    acc[4] += v1.x; acc[5] += v1.y; acc[6] += v1.z; acc[7] += v1.w;
    u32x4 pk;
    pk.x = cvtpk(v0.x, v0.y); pk.y = cvtpk(v0.z, v0.w);
    pk.z = cvtpk(v1.x, v1.y); pk.w = cvtpk(v1.z, v1.w);
    *(us8*)(xw + sb) = __builtin_bit_cast(us8, pk);
  }
  float* o = pxs + (size_t)bb * 8192 + e0;
  *(float4*)o = make_float4(acc[0], acc[1], acc[2], acc[3]);
  *(float4*)(o + 4) = make_float4(acc[4], acc[5], acc[6], acc[7]);
}

// x recompute (feature-major) + segmean partials, or pool partials at LAST.
template<int LAST>
__global__ __launch_bounds__(256) void k_xpart(const unsigned short* __restrict__ h1T,
    const unsigned short* __restrict__ h2T, const float* __restrict__ bnA,
    const float* __restrict__ bnB, const float* __restrict__ bnsA,
    const float* __restrict__ bnsB, float* __restrict__ pxsT,
    float* __restrict__ ppool) {
  int b2 = blockIdx.x, bb = b2 >> 2, c = b2 & 3, g = bb >> 2;
  int t = threadIdx.x;
  int d = c * 32 + (t >> 3), n0 = (t & 7) * 8;
  size_t off = (size_t)d * 64 + n0;
  float A1 = bnA[d], B1 = bnB[d];
  float A2 = bnsA[d], B2 = bnsB[d];
  float hb[8];
  {
    us8 v = *(const us8*)(h2T + (size_t)g * 8192 + off);
    #pragma unroll
    for (int j = 0; j < 8; ++j) hb[j] = fmaf(b2f(v[j]), A2, B2);
  }
  float acc[8];
  #pragma unroll
  for (int j = 0; j < 8; ++j) acc[j] = 0.f;
  for (int ss = 0; ss < 16; ++ss) {
    int s = bb * 16 + ss;
    int del = s & 63;
    us8 a = *(const us8*)(h1T + (size_t)s * 8192 + off);
    #pragma unroll
    for (int j = 0; j < 8; ++j) {
      float hv = ((n0 + j) != del) ? fmaf(b2f(a[j]), A1, B1) : 0.f;
      acc[j] += lk(hv + hb[j]);
    }
  }
  if (!LAST) {
    float* o = pxsT + (size_t)bb * 8192 + off;
    *(float4*)o       = make_float4(acc[0], acc[1], acc[2], acc[3]);
    *(float4*)(o + 4) = make_float4(acc[4], acc[5], acc[6], acc[7]);
  } else {
    float s8 = ((acc[0] + acc[1]) + (acc[2] + acc[3])) + ((acc[4] + acc[5]) + (acc[6] + acc[7]));
    s8 += __shfl_xor(s8, 1, 64);
    s8 += __shfl_xor(s8, 2, 64);
    s8 += __shfl_xor(s8, 4, 64);
    if ((t & 7) == 0) ppool[(size_t)bb * 128 + d] = s8;
  }
}

// Fused GIN, merged grid: blocks 0..4095 subgraph branch, 4096..4159 graph branch.
// FIRST: row-major staging (xw / pxs row-major) + LDS transpose. !FIRST:
// feature-major staging recomputing x^T from h1T (+BN1) and h2prev (+BN2 scalar).
// Output: hT[d][m] (feature-major), BN partials from registers.
template<int FIRST>
__global__ __launch_bounds__(512, 4) void k_gin(
    const unsigned short* __restrict__ xw, unsigned short* __restrict__ h1T,
    const unsigned short* __restrict__ h2prev, unsigned short* __restrict__ h2out,
    const float* __restrict__ pxs,
    const unsigned short* __restrict__ badj, const unsigned short* __restrict__ boadj,
    const unsigned short* __restrict__ W1g, const unsigned short* __restrict__ W2g,
    const unsigned short* __restrict__ W1s, const unsigned short* __restrict__ W2s,
    const float* __restrict__ b1g, const float* __restrict__ b2g,
    const float* __restrict__ b1s, const float* __restrict__ b2s,
    const float* __restrict__ epg, const float* __restrict__ epss,
    const float* __restrict__ bnA, const float* __restrict__ bnB,
    const float* __restrict__ bnsA, const float* __restrict__ bnsB,
    float* __restrict__ p1s, float* __restrict__ p1q,
    float* __restrict__ p2s, float* __restrict__ p2q) {
  __shared__ __align__(16) char lds[40960];
  char* ldsAdj = lds;              // 8KB : bf16 [64][64] swz (adj + ep1*I)
  char* ldsB   = lds + 8192;       // 16KB: x^T [128][64] swz, then u [64][128] swz
  char* ldsC   = lds + 24576;      // 16KB: FIRST x_rm linear; t [64][128] swz; hT [128][64] swz

  const int tid = threadIdx.x;
  const int bid = blockIdx.x;
  const bool SUB = bid < 4096;
  const int lb = SUB ? bid : bid - 4096;
  const int wv = tid >> 6, ln = tid & 63;
  const int lr = ln & 15, lkh = ln >> 4;
  const int wrow = wv * 16 + lr;
  const float ep1 = 1.0f + (SUB ? epg[0] : epss[0]);
  const int del = SUB ? (bid & 63) : -1;
  const unsigned short* W1t = SUB ? W1g : W1s;
  const unsigned short* W2t = SUB ? W2g : W2s;

  // ---- W fragments into registers ----
  bf16x8 w1f[4], w2f[4];
  #pragma unroll
  for (int kk = 0; kk < 4; ++kk) {
    w1f[kk] = *(const bf16x8*)(W1t + (size_t)wrow * 128 + kk * 32 + lkh * 8);
    w2f[kk] = *(const bf16x8*)(W2t + (size_t)wrow * 128 + kk * 32 + lkh * 8);
  }
  const float bb1 = (SUB ? b1g : b1s)[wrow];
  const float bb2 = (SUB ? b2g : b2s)[wrow];

  // ---- stage adj from bit-pack (+ep1 on diagonal) ----
  {
    const unsigned char* bits =
        (const unsigned char*)(SUB ? badj + (size_t)lb * 256 : boadj + (size_t)lb * 256);
    unsigned char bbt = bits[tid];
    int row = tid >> 3, o = tid & 7;
    unsigned short ep1b = f2b(ep1);
    us8 v;
    #pragma unroll
    for (int j = 0; j < 8; ++j) v[j] = ((bbt >> j) & 1) ? (unsigned short)0x3F80 : (unsigned short)0;
    int j0 = row - o * 8;
    if (j0 >= 0 && j0 < 8) v[j0] = ep1b;
    int e = tid * 8;
    *(us8*)(ldsAdj + ((e << 1) ^ ((row & 7) << 4))) = v;
  }
  // ---- stage x ----
  if (FIRST) {
    if (SUB) {
      const unsigned short* xg = xw + (size_t)bid * 8192;
      for (int e = tid * 8; e < 8192; e += 4096)
        *(us8*)(ldsC + e * 2) = *(const us8*)(xg + e);
    } else {
      const float* p = pxs + (size_t)lb * 4 * 8192;
      int e0 = tid * 16;
      #pragma unroll
      for (int cc = 0; cc < 4; ++cc) {
        float4 s = {0.f, 0.f, 0.f, 0.f};
        #pragma unroll
        for (int qt = 0; qt < 4; ++qt) {
          float4 v = *(const float4*)(p + qt * 8192 + e0 + cc * 4);
          s.x += v.x; s.y += v.y; s.z += v.z; s.w += v.w;
        }
        u32x2 pk;
        pk.x = cvtpk(s.x * 0.015625f, s.y * 0.015625f);
        pk.y = cvtpk(s.z * 0.015625f, s.w * 0.015625f);
        *(us4*)(ldsC + (e0 + cc * 4) * 2) = __builtin_bit_cast(us4, pk);
      }
    }
    __syncthreads();
    // transpose x_rm -> ldsB = x^T [128][64] swz
    int d = tid & 127, mg = (tid >> 7) * 16;
    #pragma unroll
    for (int mb = 0; mb < 16; mb += 8) {
      us8 v;
      #pragma unroll
      for (int j = 0; j < 8; ++j)
        v[j] = *(const unsigned short*)(ldsC + ((mg + mb + j) << 8) + (d << 1));
      *(us8*)(ldsB + (((d << 7) + ((mg + mb) << 1)) ^ ((d & 7) << 4))) = v;
    }
  } else {
    int d = tid >> 2, n0 = (tid & 3) * 16;    // feature row, 16 nodes
    if (SUB) {
      const unsigned short* h1g = h1T + (size_t)bid * 8192 + d * 64 + n0;
      const unsigned short* h2g = h2prev + (size_t)(bid >> 6) * 8192 + d * 64 + n0;
      float A1 = bnA[d], B1 = bnB[d];
      float A2 = bnsA[d], B2 = bnsB[d];
      #pragma unroll
      for (int cc = 0; cc < 2; ++cc) {
        us8 a = *(const us8*)(h1g + cc * 8);
        us8 b = *(const us8*)(h2g + cc * 8);
        float xv[8];
        #pragma unroll
        for (int j = 0; j < 8; ++j) {
          int m = n0 + cc * 8 + j;
          float hv = (m != del) ? fmaf(b2f(a[j]), A1, B1) : 0.f;
          xv[j] = lk(hv + fmaf(b2f(b[j]), A2, B2));
        }
        u32x4 pk;
        pk.x = cvtpk(xv[0], xv[1]); pk.y = cvtpk(xv[2], xv[3]);
        pk.z = cvtpk(xv[4], xv[5]); pk.w = cvtpk(xv[6], xv[7]);
        *(us8*)(ldsB + (((d * 64 + n0 + cc * 8) * 2) ^ ((d & 7) << 4))) = __builtin_bit_cast(us8, pk);
      }
    } else {
      const float* p = pxs + (size_t)lb * 4 * 8192 + d * 64 + n0;  // pxsT
      #pragma unroll
      for (int cc = 0; cc < 4; ++cc) {
        float4 s = {0.f, 0.f, 0.f, 0.f};
        #pragma unroll
        for (int qt = 0; qt < 4; ++qt) {
          float4 v = *(const float4*)(p + qt * 8192 + cc * 4);
          s.x += v.x; s.y += v.y; s.z += v.z; s.w += v.w;
        }
        u32x2 pk;
        pk.x = cvtpk(s.x * 0.015625f, s.y * 0.015625f);
        pk.y = cvtpk(s.z * 0.015625f, s.w * 0.015625f);
        *(us4*)(ldsB + (((d * 64 + n0 + cc * 4) * 2) ^ ((d & 7) << 4))) = __builtin_bit_cast(us4, pk);
      }
    }
  }
  __syncthreads();

  // ---- mm1: t = (adj+ep1*I) @ x -> ldsC [64][128] swz ----
  {
    f32x4 acc[4] = {};
    #pragma unroll
    for (int rt = 0; rt < 4; ++rt) {
      #pragma unroll
      for (int k0 = 0; k0 < 64; k0 += 32) {
        bf16x8 a = frag(ldsAdj, rt * 16 + lr, 64, k0 + lkh * 8);
        bf16x8 b = frag(ldsB, wrow, 64, k0 + lkh * 8);
        acc[rt] = mm(a, b, acc[rt]);
      }
    }
    #pragma unroll
    for (int rt = 0; rt < 4; ++rt) {
      unsigned p01 = cvtpk(acc[rt][0], acc[rt][1]);
      unsigned p23 = cvtpk(acc[rt][2], acc[rt][3]);
      int r0 = rt * 16 + lkh * 4;
      *(unsigned short*)(ldsC + ((((r0 + 0) << 8) + (wrow << 1)) ^ (((r0 + 0) & 7) << 4))) = (unsigned short)p01;
      *(unsigned short*)(ldsC + ((((r0 + 1) << 8) + (wrow << 1)) ^ (((r0 + 1) & 7) << 4))) = (unsigned short)(p01 >> 16);
      *(unsigned short*)(ldsC + ((((r0 + 2) << 8) + (wrow << 1)) ^ (((r0 + 2) & 7) << 4))) = (unsigned short)p23;
      *(unsigned short*)(ldsC + ((((r0 + 3) << 8) + (wrow << 1)) ^ (((r0 + 3) & 7) << 4))) = (unsigned short)(p23 >> 16);
    }
  }
  __syncthreads();

  // ---- mm2: u = leaky(t @ W1 + b1) -> ldsB [64][128] swz ----
  #pragma unroll
  for (int rt = 0; rt < 4; ++rt) {
    f32x4 acc = {};
    #pragma unroll
    for (int kk = 0; kk < 4; ++kk) {
      bf16x8 a = frag(ldsC, rt * 16 + lr, 128, kk * 32 + lkh * 8);
      acc = mm(a, w1f[kk], acc);
    }
    float u0 = lk(acc[0] + bb1), u1 = lk(acc[1] + bb1);
    float u2 = lk(acc[2] + bb1), u3 = lk(acc[3] + bb1);
    unsigned p01 = cvtpk(u0, u1);
    unsigned p23 = cvtpk(u2, u3);
    int r0 = rt * 16 + lkh * 4;
    *(unsigned short*)(ldsB + ((((r0 + 0) << 8) + (wrow << 1)) ^ (((r0 + 0) & 7) << 4))) = (unsigned short)p01;
    *(unsigned short*)(ldsB + ((((r0 + 1) << 8) + (wrow << 1)) ^ (((r0 + 1) & 7) << 4))) = (unsigned short)(p01 >> 16);
    *(unsigned short*)(ldsB + ((((r0 + 2) << 8) + (wrow << 1)) ^ (((r0 + 2) & 7) << 4))) = (unsigned short)p23;
    *(unsigned short*)(ldsB + ((((r0 + 3) << 8) + (wrow << 1)) ^ (((r0 + 3) & 7) << 4))) = (unsigned short)(p23 >> 16);
  }
  __syncthreads();

  // ---- mm3: h = u @ W2 + b2, mask; write hT [128][64] swz + reg BN partials ----
  {
    float sm = 0.f, sq = 0.f;
    #pragma unroll
    for (int rt = 0; rt < 4; ++rt) {
      f32x4 acc = {};
      #pragma unroll
      for (int kk = 0; kk < 4; ++kk) {
        bf16x8 a = frag(ldsB, rt * 16 + lr, 128, kk * 32 + lkh * 8);
        acc = mm(a, w2f[kk], acc);
      }
      float v0 = acc[0] + bb2, v1 = acc[1] + bb2, v2 = acc[2] + bb2, v3 = acc[3] + bb2;
      int m0 = rt * 16 + lkh * 4;
      if (m0 + 0 == del) v0 = 0.f;
      if (m0 + 1 == del) v1 = 0.f;
      if (m0 + 2 == del) v2 = 0.f;
      if (m0 + 3 == del) v3 = 0.f;
      sm += v0 + v1 + v2 + v3;
      sq += v0 * v0 + v1 * v1 + v2 * v2 + v3 * v3;
      u32x2 pk;
      pk.x = cvtpk(v0, v1);
      pk.y = cvtpk(v2, v3);
      *(us4*)(ldsC + (((wrow * 64 + m0) * 2) ^ ((wrow & 7) << 4))) = __builtin_bit_cast(us4, pk);
    }
    sm += __shfl_xor(sm, 16, 64); sm += __shfl_xor(sm, 32, 64);
    sq += __shfl_xor(sq, 16, 64); sq += __shfl_xor(sq, 32, 64);
    if (ln < 16) {
      float* ps = SUB ? p1s + (size_t)bid * 128 : p2s + (size_t)lb * 128;
      float* pq = SUB ? p1q + (size_t)bid * 128 : p2q + (size_t)lb * 128;
      ps[wrow] = sm;
      pq[wrow] = sq;
    }
  }
  __syncthreads();

  // ---- global write hT (linear, coalesced) ----
  unsigned short* hout = SUB ? h1T + (size_t)bid * 8192 : h2out + (size_t)lb * 8192;
  {
    int e0 = tid * 16;
    int d = e0 >> 6;
    *(us8*)(hout + e0)     = *(const us8*)(ldsC + (((e0)     * 2) ^ ((d & 7) << 4)));
    *(us8*)(hout + e0 + 8) = *(const us8*)(ldsC + (((e0 + 8) * 2) ^ ((d & 7) << 4)));
  }
}

// BN stage-1 reduce, coalesced
__global__ __launch_bounds__(256) void k_bnred(const float* __restrict__ p1s,
    const float* __restrict__ p1q, float* __restrict__ q1s, float* __restrict__ q1q) {
  __shared__ float red[512];
  int b = blockIdx.x, tid = threadIdx.x;
  int d = tid & 127, jh = tid >> 7;
  float s = 0.f, q = 0.f;
  for (int j = b * 64 + jh; j < b * 64 + 64; j += 2) {
    s += p1s[(size_t)j * 128 + d];
    q += p1q[(size_t)j * 128 + d];
  }
  red[tid] = s; red[256 + tid] = q;
  __syncthreads();
  if (tid < 128) {
    q1s[(size_t)b * 128 + d] = red[d] + red[d + 128];
    q1q[(size_t)b * 128 + d] = red[256 + d] + red[384 + d];
  }
}

// Finalize BN into fused scale/shift
__global__ __launch_bounds__(128) void k_bnfin(const float* __restrict__ q1s,
    const float* __restrict__ q1q, const float* __restrict__ p2s,
    const float* __restrict__ p2q, const float* __restrict__ gam1,
    const float* __restrict__ bet1, const float* __restrict__ gam2,
    const float* __restrict__ bet2, float* __restrict__ bnA, float* __restrict__ bnB,
    float* __restrict__ bnsA, float* __restrict__ bnsB) {
  int d = threadIdx.x;
  float s = 0.f, q = 0.f, s2 = 0.f, q2 = 0.f;
  for (int j = 0; j < 64; ++j) {
    s  += q1s[j * 128 + d];  q  += q1q[j * 128 + d];
    s2 += p2s[j * 128 + d];  q2 += p2q[j * 128 + d];
  }
  const float cnt1 = 4096.0f * 63.0f;
  float mean = s / cnt1;
  float var = q / cnt1 - mean * mean;
  float A = gam1[d] * rsqrtf(var + 1e-5f);
  bnA[d] = A; bnB[d] = bet1[d] - mean * A;
  float mean2 = s2 / 4096.0f;
  float var2 = q2 / 4096.0f - mean2 * mean2;
  float A2 = gam2[d] * rsqrtf(var2 + 1e-5f);
  bnsA[d] = A2; bnsB[d] = bet2[d] - mean2 * A2;
}

// final readout MLP per graph, fp32 out
__global__ __launch_bounds__(256) void k_final(const float* __restrict__ ppool,
    const float* __restrict__ W1, const float* __restrict__ b1,
    const float* __restrict__ W2, const float* __restrict__ b2,
    float* __restrict__ out) {
  __shared__ float hg[128];
  __shared__ float z[256];
  int g = blockIdx.x, t = threadIdx.x;
  if (t < 128) {
    float s = ppool[(size_t)(g * 4 + 0) * 128 + t] + ppool[(size_t)(g * 4 + 1) * 128 + t]
            + ppool[(size_t)(g * 4 + 2) * 128 + t] + ppool[(size_t)(g * 4 + 3) * 128 + t];
    hg[t] = s * (1.0f / (63.0f * 64.0f));
  }
  __syncthreads();
  float a = b1[t];
  for (int d = 0; d < 128; ++d) a = fmaf(hg[d], W1[d * 256 + t], a);
  z[t] = lk(a);
  __syncthreads();
  if (t < 10) {
    float o = b2[t];
    for (int j = 0; j < 256; ++j) o = fmaf(z[j], W2[j * 10 + t], o);
    out[g * 10 + t] = o;
  }
}

extern "C" void kernel_launch(void* const* d_in, const int* in_sizes, int n_in,
                              void* d_out, int out_size, void* d_ws, size_t ws_size,
                              hipStream_t stream) {
  (void)in_sizes; (void)n_in; (void)out_size; (void)ws_size;
  const float* x    = (const float*)d_in[0];
  const float* adj  = (const float*)d_in[1];
  const float* oadj = (const float*)d_in[2];
  const float* gW1  = (const float*)d_in[3];
  const float* gb1  = (const float*)d_in[4];
  const float* gW2  = (const float*)d_in[5];
  const float* gb2  = (const float*)d_in[6];
  const float* geps = (const float*)d_in[7];
  const float* sW1  = (const float*)d_in[8];
  const float* sb1  = (const float*)d_in[9];
  const float* sW2  = (const float*)d_in[10];
  const float* sb2  = (const float*)d_in[11];
  const float* seps = (const float*)d_in[12];
  const float* bng  = (const float*)d_in[13];
  const float* bnb  = (const float*)d_in[14];
  const float* bnsg = (const float*)d_in[15];
  const float* bnsb = (const float*)d_in[16];
  const float* fW1  = (const float*)d_in[17];
  const float* fb1  = (const float*)d_in[18];
  const float* fW2  = (const float*)d_in[19];
  const float* fb2  = (const float*)d_in[20];
  float* out = (float*)d_out;

  char* w = (char*)d_ws;
  unsigned short* xw   = (unsigned short*)w; w += 67108864;   // x0 bf16 row-major
  unsigned short* h1T  = (unsigned short*)w; w += 67108864;   // h1 bf16 feature-major
  unsigned short* h2a  = (unsigned short*)w; w += 1048576;    // h2 ping (feature-major)
  unsigned short* h2b  = (unsigned short*)w; w += 1048576;    // h2 pong
  unsigned short* badj = (unsigned short*)w; w += 2097152;    // adj bits
  unsigned short* boadj= (unsigned short*)w; w += 32768;      // oadj bits
  unsigned short* wt   = (unsigned short*)w; w += 524288;     // 16x W^T bf16
  float* pxs  = (float*)w;          w += 8388608;             // xsum partials [256][8192]
  float* p1s  = (float*)w;          w += 2097152;
  float* p1q  = (float*)w;          w += 2097152;
  float* p2s  = (float*)w;          w += 32768;
  float* p2q  = (float*)w;          w += 32768;
  float* q1s  = (float*)w;          w += 32768;
  float* q1q  = (float*)w;          w += 32768;
  float* bnA  = (float*)w;          w += 512;
  float* bnB  = (float*)w;          w += 512;
  float* bnsA = (float*)w;          w += 512;
  float* bnsB = (float*)w;          w += 512;
  float* ppool= (float*)w;          w += 131072;              // [256][128]

  unsigned short* h2buf[2] = {h2a, h2b};

  k_prep<<<16, 256, 0, stream>>>(gW1, gW2, sW1, sW2, wt);
  k_pack<<<4160, 256, 0, stream>>>(adj, oadj, badj, boadj);
  k_castseg<<<1024, 256, 0, stream>>>(x, xw, pxs);

  for (int i = 0; i < 4; ++i) {
    unsigned short* h2prev = h2buf[(i + 1) & 1];   // layer i-1 output (i>=1)
    unsigned short* h2cur  = h2buf[i & 1];
    if (i > 0)
      k_xpart<0><<<1024, 256, 0, stream>>>(h1T, h2prev, bnA, bnB, bnsA, bnsB, pxs, ppool);
    if (i == 0)
      k_gin<1><<<4160, 512, 0, stream>>>(xw, h1T, h2prev, h2cur, pxs, badj, boadj,
          wt + 0 * 16384, wt + 1 * 16384, wt + 2 * 16384, wt + 3 * 16384,
          gb1, gb2, sb1, sb2, geps, seps, bnA, bnB, bnsA, bnsB, p1s, p1q, p2s, p2q);
    else
      k_gin<0><<<4160, 512, 0, stream>>>(xw, h1T, h2prev, h2cur, pxs, badj, boadj,
          wt + (i * 4 + 0) * 16384, wt + (i * 4 + 1) * 16384,
          wt + (i * 4 + 2) * 16384, wt + (i * 4 + 3) * 16384,
          gb1 + i * 128, gb2 + i * 128, sb1 + i * 128, sb2 + i * 128,
          geps + i, seps + i, bnA, bnB, bnsA, bnsB, p1s, p1q, p2s, p2q);
    k_bnred<<<64, 256, 0, stream>>>(p1s, p1q, q1s, q1q);
    k_bnfin<<<1, 128, 0, stream>>>(q1s, q1q, p2s, p2q, bng + i * 128,
        bnb + i * 128, bnsg + i * 128, bnsb + i * 128, bnA, bnB, bnsA, bnsB);
  }
  k_xpart<1><<<1024, 256, 0, stream>>>(h1T, h2buf[1], bnA, bnB, bnsA, bnsB, pxs, ppool);
  k_final<<<64, 256, 0, stream>>>(ppool, fW1, fb1, fW2, fb2, out);
}